// Round 1
// baseline (322.494 us; speedup 1.0000x reference)
//
#include <hip/hip_runtime.h>

#define B_    8192
#define T_    240
#define C_    16
#define DAYS_ 10
#define W_    24                 // (240-10)/10 + 1
#define NROWS (B_ * W_)          // 196608
#define PAIRS 120                // 16*15/2
#define OUTC  320                // 2*120 + 5*16
#define EPS_F 1e-8f
#define EPS_BN 1e-5f

#define STATS_BLOCKS 768
#define ROWS_PER_BLOCK (NROWS / STATS_BLOCKS)  // 256

// ---------------- Phase 1: per-row feature extraction ----------------
// Row r = b*24 + w reads contiguous x[r*160 .. r*160+159] (windows tile T).
__global__ __launch_bounds__(256)
void feat_kernel(const float* __restrict__ x, float* __restrict__ f) {
    int r = blockIdx.x * blockDim.x + threadIdx.x;
    if (r >= NROWS) return;

    const float4* src = reinterpret_cast<const float4*>(x + (size_t)r * (DAYS_ * C_));
    float win[DAYS_][C_];
#pragma unroll
    for (int q = 0; q < DAYS_ * C_ / 4; ++q) {
        float4 v = src[q];
        int d = q / 4, c = (q % 4) * 4;
        win[d][c + 0] = v.x; win[d][c + 1] = v.y;
        win[d][c + 2] = v.z; win[d][c + 3] = v.w;
    }

    float* out = f + (size_t)r * OUTC;

    // mean
    float mean[C_];
#pragma unroll
    for (int c = 0; c < C_; ++c) {
        float s = 0.f;
#pragma unroll
        for (int d = 0; d < DAYS_; ++d) s += win[d][c];
        mean[c] = s * (1.0f / DAYS_);
    }

    // ret (272..287), decay (288..303), mean (304..319)
#pragma unroll
    for (int c = 0; c < C_; ++c)
        out[272 + c] = win[DAYS_ - 1][c] / win[0][c] - 1.0f;
#pragma unroll
    for (int c = 0; c < C_; ++c) {
        float s = 0.f;
#pragma unroll
        for (int d = 0; d < DAYS_; ++d)
            s += win[d][c] * ((float)(d + 1) / (DAYS_ * (DAYS_ + 1) / 2));
        out[288 + c] = s;
    }
#pragma unroll
    for (int c = 0; c < C_; ++c) out[304 + c] = mean[c];

    // overwrite win with dx = win - mean
#pragma unroll
    for (int d = 0; d < DAYS_; ++d)
#pragma unroll
        for (int c = 0; c < C_; ++c) win[d][c] -= mean[c];

    // std (240..255), zscore (256..271)
    float stdv[C_];
#pragma unroll
    for (int c = 0; c < C_; ++c) {
        float s = 0.f;
#pragma unroll
        for (int d = 0; d < DAYS_; ++d) s += win[d][c] * win[d][c];
        stdv[c] = sqrtf(s * (1.0f / DAYS_));
        out[240 + c] = stdv[c];
        out[256 + c] = mean[c] / (stdv[c] + EPS_F);
    }

    // corr (0..119), cov (120..239) — triu order (0,1),(0,2),...,(14,15)
    int p = 0;
#pragma unroll
    for (int i = 0; i < C_; ++i) {
#pragma unroll
        for (int j = i + 1; j < C_; ++j) {
            float s = 0.f;
#pragma unroll
            for (int d = 0; d < DAYS_; ++d) s += win[d][i] * win[d][j];
            float cv = s * (1.0f / DAYS_);
            out[p] = cv / (stdv[i] * stdv[j] + EPS_F);
            out[120 + p] = cv;
            ++p;
        }
    }
}

// ---------------- Phase 2: per-block partial BN sums ----------------
// One block per 256-row chunk; thread t owns channel t (coalesced reads).
__global__ __launch_bounds__(OUTC)
void stats_kernel(const float* __restrict__ f, float* __restrict__ partial) {
    int c = threadIdx.x;
    int r0 = blockIdx.x * ROWS_PER_BLOCK;
    float s = 0.f, s2 = 0.f;
    for (int r = r0; r < r0 + ROWS_PER_BLOCK; ++r) {
        float v = f[(size_t)r * OUTC + c];
        s += v;
        s2 += v * v;
    }
    partial[(size_t)blockIdx.x * (2 * OUTC) + c] = s;
    partial[(size_t)blockIdx.x * (2 * OUTC) + OUTC + c] = s2;
}

// ---------------- Phase 3: finalize scale/shift ----------------
__global__ __launch_bounds__(OUTC)
void finalize_kernel(const float* __restrict__ partial,
                     const float* __restrict__ gamma,
                     const float* __restrict__ beta,
                     float* __restrict__ ab) {
    int c = threadIdx.x;
    double s = 0.0, s2 = 0.0;
    for (int k = 0; k < STATS_BLOCKS; ++k) {
        s  += (double)partial[(size_t)k * (2 * OUTC) + c];
        s2 += (double)partial[(size_t)k * (2 * OUTC) + OUTC + c];
    }
    const double invN = 1.0 / (double)NROWS;
    float m = (float)(s * invN);
    float v = (float)(s2 * invN - (double)m * (double)m);
    v = fmaxf(v, 0.0f);
    float a = gamma[c] / sqrtf(v + EPS_BN);
    ab[c] = a;
    ab[OUTC + c] = beta[c] - m * a;
}

// ---------------- Phase 4: in-place normalize ----------------
__global__ __launch_bounds__(256)
void apply_kernel(float* __restrict__ f, const float* __restrict__ ab, size_t n4) {
    size_t i = (size_t)blockIdx.x * blockDim.x + threadIdx.x;
    size_t stride = (size_t)gridDim.x * blockDim.x;
    float4* f4 = reinterpret_cast<float4*>(f);
    for (; i < n4; i += stride) {
        float4 v = f4[i];
        int c = (int)((i * 4) % OUTC);   // 320 % 4 == 0 -> c..c+3 same group
        v.x = v.x * ab[c + 0] + ab[OUTC + c + 0];
        v.y = v.y * ab[c + 1] + ab[OUTC + c + 1];
        v.z = v.z * ab[c + 2] + ab[OUTC + c + 2];
        v.w = v.w * ab[c + 3] + ab[OUTC + c + 3];
        f4[i] = v;
    }
}

extern "C" void kernel_launch(void* const* d_in, const int* in_sizes, int n_in,
                              void* d_out, int out_size, void* d_ws, size_t ws_size,
                              hipStream_t stream) {
    const float* x     = (const float*)d_in[0];
    const float* gamma = (const float*)d_in[1];
    const float* beta  = (const float*)d_in[2];
    float* f = (float*)d_out;

    float* partial = (float*)d_ws;                          // 768*640 floats ≈ 1.97 MB
    float* ab      = partial + (size_t)STATS_BLOCKS * 2 * OUTC;  // 640 floats

    // Phase 1: features -> d_out (unnormalized)
    feat_kernel<<<NROWS / 256, 256, 0, stream>>>(x, f);

    // Phase 2: partial sums
    stats_kernel<<<STATS_BLOCKS, OUTC, 0, stream>>>(f, partial);

    // Phase 3: scale/shift
    finalize_kernel<<<1, OUTC, 0, stream>>>(partial, gamma, beta, ab);

    // Phase 4: normalize in place
    size_t n4 = (size_t)out_size / 4;
    apply_kernel<<<2048, 256, 0, stream>>>(f, ab, n4);
}